// Round 12
// baseline (208.771 us; speedup 1.0000x reference)
//
#include <hip/hip_runtime.h>

typedef unsigned int u32;
typedef unsigned short u16;
typedef __attribute__((ext_vector_type(8))) __bf16 bf16x8;
typedef __attribute__((ext_vector_type(4))) short s16x4;
typedef __attribute__((ext_vector_type(4))) float f32x4;

#define AS1 __attribute__((address_space(1)))
#define AS3 __attribute__((address_space(3)))

__device__ __forceinline__ void gl_lds16(const void* g, void* l) {
  __builtin_amdgcn_global_load_lds((const AS1 void*)g, (AS3 void*)l, 16, 0, 0);
}

__device__ __forceinline__ u16 f2bf(float f) {
  union { float f; u32 u; } v; v.f = f;
  u32 r = v.u + 0x7fffu + ((v.u >> 16) & 1u);
  return (u16)(r >> 16);
}

__device__ __forceinline__ float bf2f(u16 b) {
  union { u32 u; float f; } v; v.u = ((u32)b) << 16; return v.f;
}

__device__ __forceinline__ u32 cvt_pk_bf16(float a, float b) {
  u32 r;
  asm("v_cvt_pk_bf16_f32 %0, %1, %2" : "=v"(r) : "v"(a), "v"(b));
  return r;
}

// 16x16x16 bf16 MFMA (PV consumes P straight from registers).
__device__ __forceinline__ f32x4 mfma16(s16x4 a, s16x4 b, f32x4 c) {
#if __has_builtin(__builtin_amdgcn_mfma_f32_16x16x16bf16_1k)
  return __builtin_amdgcn_mfma_f32_16x16x16bf16_1k(a, b, c, 0, 0, 0);
#else
  asm("v_mfma_f32_16x16x16_bf16 %0, %1, %2, %0" : "+v"(c) : "v"(a), "v"(b));
  return c;
#endif
}

// ---------------- f32 -> bf16 conversion (6 arrays, one launch) ----------------
__global__ void cvt6_kernel(const float* __restrict__ a, const float* __restrict__ b,
                            const float* __restrict__ c, const float* __restrict__ wq,
                            const float* __restrict__ wk, const float* __restrict__ wv,
                            u16* __restrict__ oa, u16* __restrict__ ob, u16* __restrict__ oc,
                            u16* __restrict__ owq, u16* __restrict__ owk, u16* __restrict__ owv,
                            int n4in, int n4w) {
  const int y = blockIdx.y;
  const float* in = (y == 0) ? a : (y == 1) ? b : (y == 2) ? c :
                    (y == 3) ? wq : (y == 4) ? wk : wv;
  u16* out = (y == 0) ? oa : (y == 1) ? ob : (y == 2) ? oc :
             (y == 3) ? owq : (y == 4) ? owk : owv;
  const int n4 = (y < 3) ? n4in : n4w;
  int i = blockIdx.x * blockDim.x + threadIdx.x;
  if (i >= n4) return;
  float4 v = ((const float4*)in)[i];
  ushort4 o;
  o.x = f2bf(v.x); o.y = f2bf(v.y); o.z = f2bf(v.z); o.w = f2bf(v.w);
  ((ushort4*)out)[i] = o;
}

// ---------------- projection GEMM: C[m,n] = sum_k X[m,k] W[n,k] ----------------
// 128x128 tile, BK=32, 4 waves. R12: TRIPLE-buffered staging, prefetch
// distance 2, counted vmcnt(8) barriers (attn-proven T3/T4 pattern) -- the
// barrier retires only the PREVIOUS iteration's 8 staging loads; the 8 just
// issued stay in flight. Grid (32,8,3): X-panels XCD-local. Epilogue: in-lane
// bf16 pack -> LDS transpose (reusing stage buffers) -> 1KB full-line stores.
__global__ void __launch_bounds__(256) proj_gemm(
    const u16* __restrict__ Xq, const u16* __restrict__ Xk, const u16* __restrict__ Xv,
    const u16* __restrict__ Wq, const u16* __restrict__ Wk, const u16* __restrict__ Wv,
    u16* __restrict__ Qo, u16* __restrict__ Ko, u16* __restrict__ Vto)
{
  const int which = blockIdx.z;
  const u16* X = (which == 0) ? Xq : (which == 1) ? Xk : Xv;
  const u16* W = (which == 0) ? Wq : (which == 1) ? Wk : Wv;
  const bool isV = (which == 2);

  // 48KB: 3 x (As 4096 u16 + Bs 4096 u16). Epilogue reuses first 34KB as the
  // 128-row x 272B transpose scratch.
  __shared__ u16 smem[3 * 8192];

  const int t = threadIdx.x;
  const int lane = t & 63;
  const int w = t >> 6;
  const int wr = w >> 1, wc = w & 1;
  const int lr = lane & 15, lg = lane >> 4;
  const int m0 = blockIdx.x * 128, n0 = blockIdx.y * 128;

  const int e0 = t * 8, e1 = t * 8 + 2048;
  const int r0 = e0 >> 5, c0 = e0 & 31, r1 = e1 >> 5, c1 = e1 & 31;

  // operand-order mapping (wave-uniform, no divergence):
  const int uo = isV ? wr * 64 : wc * 64;   // u-frag row offset (output-row space)
  const int vo = isV ? wc * 64 : wr * 64;   // v-frag row offset (output-col space)

  const f32x4 ZERO = {0.f, 0.f, 0.f, 0.f};
  f32x4 acc[4][4];
  for (int p = 0; p < 4; ++p)
    for (int q = 0; q < 4; ++q) acc[p][q] = ZERO;

  // prologue: stage k-steps 0 and 1 into buffers 0 and 1
#pragma unroll
  for (int pk = 0; pk < 2; ++pk) {
    u16* As = &smem[pk * 8192];
    u16* Bs = As + 4096;
    int kn = pk * 32;
    gl_lds16(&X[(size_t)(m0 + r0) * 1024 + kn + c0], &As[e0]);
    gl_lds16(&X[(size_t)(m0 + r1) * 1024 + kn + c1], &As[e1]);
    gl_lds16(&W[(size_t)(n0 + r0) * 1024 + kn + c0], &Bs[e0]);
    gl_lds16(&W[(size_t)(n0 + r1) * 1024 + kn + c1], &Bs[e1]);
  }
  // wait buffer 0 only (8 oldest); buffer 1's 8 loads stay in flight
  __builtin_amdgcn_sched_barrier(0);
  asm volatile("s_waitcnt vmcnt(8)" ::: "memory");
  __builtin_amdgcn_s_barrier();
  __builtin_amdgcn_sched_barrier(0);

  for (int ks = 0; ks < 32; ++ks) {
    if (ks + 2 < 32) {                      // prefetch distance 2
      int kn = (ks + 2) * 32;
      u16* As = &smem[((ks + 2) % 3) * 8192];
      u16* Bs = As + 4096;
      gl_lds16(&X[(size_t)(m0 + r0) * 1024 + kn + c0], &As[e0]);
      gl_lds16(&X[(size_t)(m0 + r1) * 1024 + kn + c1], &As[e1]);
      gl_lds16(&W[(size_t)(n0 + r0) * 1024 + kn + c0], &Bs[e0]);
      gl_lds16(&W[(size_t)(n0 + r1) * 1024 + kn + c1], &Bs[e1]);
    }
    const u16* Ab = &smem[(ks % 3) * 8192];
    const u16* Bb = Ab + 4096;
    const u16* ub = isV ? Ab : Bb;
    const u16* vb = isV ? Bb : Ab;
    bf16x8 u[4], v[4];
#pragma unroll
    for (int p = 0; p < 4; ++p)
      u[p] = *(const bf16x8*)&ub[(uo + p * 16 + lr) * 32 + lg * 8];
#pragma unroll
    for (int q = 0; q < 4; ++q)
      v[q] = *(const bf16x8*)&vb[(vo + q * 16 + lr) * 32 + lg * 8];
#pragma unroll
    for (int p = 0; p < 4; ++p)
#pragma unroll
      for (int q = 0; q < 4; ++q)
        acc[p][q] = __builtin_amdgcn_mfma_f32_16x16x32_bf16(u[p], v[q], acc[p][q], 0, 0, 0);

    if (ks < 31) {
      // retire stage(ks+1) (issued last iter); stage(ks+2)'s 8 stay in flight
      __builtin_amdgcn_sched_barrier(0);
      if (ks == 30) { asm volatile("s_waitcnt vmcnt(0)" ::: "memory"); }
      else          { asm volatile("s_waitcnt vmcnt(8)" ::: "memory"); }
      __builtin_amdgcn_s_barrier();
      __builtin_amdgcn_sched_barrier(0);
    }
  }

  // ---- epilogue: pack in-lane (output-row consecutive) -> LDS transpose ----
  __syncthreads();                      // stage buffers dead, reuse as scratch
#pragma unroll
  for (int p = 0; p < 4; ++p) {
#pragma unroll
    for (int q = 0; q < 4; ++q) {
      u32 lo = cvt_pk_bf16(acc[p][q][0], acc[p][q][1]);
      u32 hi = cvt_pk_bf16(acc[p][q][2], acc[p][q][3]);
      int row = vo + q * 16 + lr;       // output-col space (m for QK, n for V)
      int col = uo + p * 16 + lg * 4;   // output-row space (n for QK, m for V)
      *(uint2*)((char*)smem + row * 272 + col * 2) = make_uint2(lo, hi);
    }
  }
  __syncthreads();

  const int h0 = (n0 >> 6);             // first head of this n-panel
  if (!isV) {
    // scratch[m][n]; line = (s, head): 64 d x 2B = 128B. 8 rows x 128B = 1KB/inst.
    u16* O = (which == 0) ? Qo : Ko;
#pragma unroll
    for (int hd = 0; hd < 2; ++hd) {
#pragma unroll
      for (int sb = 0; sb < 4; ++sb) {
        int srow = w * 32 + sb * 8 + (lane >> 3);
        int c = lane & 7;
        uint4 val = *(const uint4*)((const char*)smem + srow * 272 + hd * 128 + c * 16);
        int m = m0 + srow;
        int bb = m >> 11, s = m & 2047;
        *(uint4*)(O + ((size_t)(bb * 16 + h0 + hd) * 2048 + s) * 64 + c * 8) = val;
      }
    }
  } else {
    // scratch[n][m]; line = (head,d): 128 s x 2B = 256B. 4 rows x 256B = 1KB/inst.
    const int bb = m0 >> 11;
    const int sbase = m0 & 2047;        // per-batch row offset
#pragma unroll
    for (int rb = 0; rb < 8; ++rb) {
      int nloc = w * 32 + rb * 4 + (lane >> 4);
      int c = lane & 15;
      uint4 val = *(const uint4*)((const char*)smem + nloc * 272 + c * 16);
      int hd = nloc >> 6, dloc = nloc & 63;
      *(uint4*)(Vto + ((size_t)(bb * 16 + h0 + hd) * 64 + dloc) * 2048 + sbase + c * 8) = val;
    }
  }
}

// ---------------- fused attention: denom + attn write + PV ----------------
// (R9-proven) 8 waves, QBLK=128, KVBLK=64, triple-buffered staging, prefetch
// distance 2, counted-vmcnt barriers, reg-P PV, per-wave LDS transpose of the
// attn f32 tile -> full-line 128B global stores. R12: clamp dropped (scores
// ~N(0,1); exp overflow needs s>88).
__global__ void __launch_bounds__(512, 4) attn_fused(
    const u16* __restrict__ Qw, const u16* __restrict__ Kw, const u16* __restrict__ VTw,
    float* __restrict__ attn_out, u16* __restrict__ ctx)
{
  __shared__ u16 Ks[3][64 * 64];    // 24KB
  __shared__ u16 Vs[3][64 * 64];    // 24KB
  __shared__ float Pf[8][16 * 36];  // 18KB per-wave f32 P-tile (stride 36 floats)

  const int t = threadIdx.x, lane = t & 63, w = t >> 6;
  const int lr = lane & 15, lg = lane >> 4;
  const int orig = blockIdx.x;
  const int lin = (orig & 7) * 64 + (orig >> 3);   // XCD-chunked bijective (512=8*64)
  const int bh = lin >> 4, q0 = (lin & 15) * 128;

  const u16* Qbase = Qw + (size_t)bh * 2048 * 64;
  const u16* Kbase = Kw + (size_t)bh * 2048 * 64;
  const u16* VTbase = VTw + (size_t)bh * 64 * 2048;

  const int qrow = q0 + w * 16 + lr;
  bf16x8 qa[2];
#pragma unroll
  for (int sl = 0; sl < 2; ++sl)
    qa[sl] = *(const bf16x8*)&Qbase[(size_t)qrow * 64 + sl * 32 + lg * 8];

  const int o = t * 16;
  const int sr = o >> 7;
  const int sg = (((o >> 4) & 7) ^ (sr & 7)) << 3;

  const f32x4 ZERO = {0.f, 0.f, 0.f, 0.f};

  // ================= phase 1: softmax denominator =================
  gl_lds16(&Kbase[(size_t)sr * 64 + sg], (char*)&Ks[0][0] + o);
  gl_lds16(&Kbase[(size_t)(64 + sr) * 64 + sg], (char*)&Ks[1][0] + o);
  __syncthreads();

  float lacc = 0.f;
  for (int it = 0; it < 32; ++it) {
    if (it + 2 < 32)
      gl_lds16(&Kbase[(size_t)((it + 2) * 64 + sr) * 64 + sg],
               (char*)&Ks[(it + 2) % 3][0] + o);
    const u16* Kb = &Ks[it % 3][0];
    f32x4 sacc[4];
#pragma unroll
    for (int jj = 0; jj < 4; ++jj) sacc[jj] = ZERO;
#pragma unroll
    for (int sl = 0; sl < 2; ++sl) {
#pragma unroll
      for (int jj = 0; jj < 4; ++jj) {
        int R = jj * 16 + lr;
        int gs = lg + sl * 4;
        bf16x8 kb = *(const bf16x8*)&Kb[R * 64 + ((gs ^ (R & 7)) << 3)];
        sacc[jj] = __builtin_amdgcn_mfma_f32_16x16x32_bf16(kb, qa[sl], sacc[jj], 0, 0, 0);
      }
    }
#pragma unroll
    for (int jj = 0; jj < 4; ++jj)
#pragma unroll
      for (int r = 0; r < 4; ++r)
        lacc += __expf(sacc[jj][r] * 0.125f);

    if (it < 31) {
      __builtin_amdgcn_sched_barrier(0);
      if (it == 30) { asm volatile("s_waitcnt vmcnt(0)" ::: "memory"); }
      else         { asm volatile("s_waitcnt vmcnt(2)" ::: "memory"); }
      __builtin_amdgcn_s_barrier();
      __builtin_amdgcn_sched_barrier(0);
    }
  }
  lacc += __shfl_xor(lacc, 16);
  lacc += __shfl_xor(lacc, 32);               // l for q = qrow (uniform over lg)
  const float linv = 1.f / lacc;

  // ================= phase 2: attn write + PV =================
  __syncthreads();                            // all phase-1 LDS reads done
  gl_lds16(&Kbase[(size_t)sr * 64 + sg], (char*)&Ks[0][0] + o);
  gl_lds16(&VTbase[(size_t)sr * 2048 + sg], (char*)&Vs[0][0] + o);
  gl_lds16(&Kbase[(size_t)(64 + sr) * 64 + sg], (char*)&Ks[1][0] + o);
  gl_lds16(&VTbase[(size_t)sr * 2048 + 64 + sg], (char*)&Vs[1][0] + o);
  __syncthreads();                            // prologue staging visible

  f32x4 acc_o[4];                             // acc_o[dd]: d = dd*16+lg*4+r, q = lr
#pragma unroll
  for (int j = 0; j < 4; ++j) acc_o[j] = ZERO;

  float* ablk = attn_out + ((size_t)bh * 2048 + q0 + w * 16) * 2048;  // wave's 16 rows
  float* Pfw = &Pf[w][0];

  for (int it = 0; it < 32; ++it) {
    const int kt = it * 64;
    if (it + 2 < 32) {                         // prefetch distance 2
      const int nb = (it + 2) % 3;
      gl_lds16(&Kbase[(size_t)(kt + 128 + sr) * 64 + sg], (char*)&Ks[nb][0] + o);
      gl_lds16(&VTbase[(size_t)sr * 2048 + kt + 128 + sg], (char*)&Vs[nb][0] + o);
    }
    const u16* Kb = &Ks[it % 3][0];
    const u16* Vb = &Vs[it % 3][0];

    // S^T tile: lane holds S[k=kt+jj*16+lg*4+r][q=qrow]
    f32x4 sacc[4];
#pragma unroll
    for (int jj = 0; jj < 4; ++jj) sacc[jj] = ZERO;
#pragma unroll
    for (int sl = 0; sl < 2; ++sl) {
#pragma unroll
      for (int jj = 0; jj < 4; ++jj) {
        int R = jj * 16 + lr;
        int gs = lg + sl * 4;
        bf16x8 kb = *(const bf16x8*)&Kb[R * 64 + ((gs ^ (R & 7)) << 3)];
        sacc[jj] = __builtin_amdgcn_mfma_f32_16x16x32_bf16(kb, qa[sl], sacc[jj], 0, 0, 0);
      }
    }

    // exp; pack P bf16 B-frags in regs; attn f32 via per-wave LDS transpose ->
    // full-line 128B global stores (8 rows x 128B per inst).
    s16x4 pb[4];
#pragma unroll
    for (int h0 = 0; h0 < 2; ++h0) {
#pragma unroll
      for (int j2 = 0; j2 < 2; ++j2) {
        const int jj = h0 * 2 + j2;
        f32x4 e;
#pragma unroll
        for (int r = 0; r < 4; ++r)
          e[r] = __expf(sacc[jj][r] * 0.125f);
        f32x4 st = e * linv;
        *(f32x4*)&Pfw[lr * 36 + j2 * 16 + lg * 4] = st;   // [q=lr][kofs]
        union { u32 w2[2]; s16x4 v; } pk;
        pk.w2[0] = cvt_pk_bf16(e[0], e[1]);
        pk.w2[1] = cvt_pk_bf16(e[2], e[3]);
        pb[jj] = pk.v;
      }
      asm volatile("s_waitcnt lgkmcnt(0)" ::: "memory");
      __builtin_amdgcn_sched_barrier(0);
#pragma unroll
      for (int rb = 0; rb < 2; ++rb) {
        const int rrow = rb * 8 + (lane >> 3);
        f32x4 v = *(const f32x4*)&Pfw[rrow * 36 + (lane & 7) * 4];
        float* dst = ablk + (size_t)rrow * 2048 + kt + h0 * 32 + (lane & 7) * 4;
        __builtin_nontemporal_store(v, (f32x4*)dst);
      }
    }

    // PV: acc_o[dd] += V^T[dd*16+lr][jj*16 + lg*4..+3] (A) * P (B, registers)
#pragma unroll
    for (int dd = 0; dd < 4; ++dd) {
      const int R = dd * 16 + lr;
      const int rowbase = R * 64;
      const int rsw = (R & 7);
#pragma unroll
      for (int jj = 0; jj < 4; ++jj) {
        const int slot = 2 * jj + (lg >> 1);
        s16x4 va = *(const s16x4*)&Vb[rowbase + ((slot ^ rsw) << 3) + (lg & 1) * 4];
        acc_o[dd] = mfma16(va, pb[jj], acc_o[dd]);
      }
    }

    if (it < 31) {
      __builtin_amdgcn_sched_barrier(0);
      if (it == 30) { asm volatile("s_waitcnt vmcnt(8)" ::: "memory"); }
      else          { asm volatile("s_waitcnt vmcnt(10)" ::: "memory"); }
      __builtin_amdgcn_s_barrier();
      __builtin_amdgcn_sched_barrier(0);
    }
  }

  // epilogue: ctx = O / l (bf16), q = lr (lane-local linv), d consecutive in r
  const int bb = bh >> 4, h = bh & 15;
  u16* crow = ctx + ((size_t)bb * 2048 + qrow) * 1024 + h * 64;
#pragma unroll
  for (int dd = 0; dd < 4; ++dd) {
    union { u32 w2[2]; } pk;
    pk.w2[0] = cvt_pk_bf16(acc_o[dd][0] * linv, acc_o[dd][1] * linv);
    pk.w2[1] = cvt_pk_bf16(acc_o[dd][2] * linv, acc_o[dd][3] * linv);
    *(uint2*)&crow[dd * 16 + lg * 4] = make_uint2(pk.w2[0], pk.w2[1]);
  }
}

// ---------------- residual + LayerNorm (ctx bf16, residual f32) ----------------
__global__ void __launch_bounds__(256) ln_kernel(
    const u16* __restrict__ ctx, const float* __restrict__ res, float* __restrict__ out)
{
  __shared__ float red[8];
  int row = blockIdx.x;
  int t = threadIdx.x;
  int lane = t & 63, w = t >> 6;
  size_t base = (size_t)row * 1024 + t * 4;
  ushort4 cv = *(const ushort4*)&ctx[base];
  float4 rs = *(const float4*)&res[base];
  float x0 = bf2f(cv.x) + rs.x, x1 = bf2f(cv.y) + rs.y;
  float x2 = bf2f(cv.z) + rs.z, x3 = bf2f(cv.w) + rs.w;
  float s = x0 + x1 + x2 + x3;
  float q = x0 * x0 + x1 * x1 + x2 * x2 + x3 * x3;
#pragma unroll
  for (int off = 1; off < 64; off <<= 1) {
    s += __shfl_xor(s, off);
    q += __shfl_xor(q, off);
  }
  if (lane == 0) { red[w] = s; red[w + 4] = q; }
  __syncthreads();
  s = red[0] + red[1] + red[2] + red[3];
  q = red[4] + red[5] + red[6] + red[7];
  float mu = s * (1.f / 1024.f);
  float var = q * (1.f / 1024.f) - mu * mu;
  float inv = rsqrtf(var + 1e-5f);
  float4 o;
  o.x = (x0 - mu) * inv; o.y = (x1 - mu) * inv; o.z = (x2 - mu) * inv; o.w = (x3 - mu) * inv;
  *(float4*)&out[base] = o;
}

extern "C" void kernel_launch(void* const* d_in, const int* in_sizes, int n_in,
                              void* d_out, int out_size, void* d_ws, size_t ws_size,
                              hipStream_t stream) {
  (void)in_sizes; (void)n_in; (void)out_size; (void)ws_size;
  const float* inQ = (const float*)d_in[0];
  const float* inK = (const float*)d_in[1];
  const float* inV = (const float*)d_in[2];
  const float* wQ  = (const float*)d_in[3];
  const float* wK  = (const float*)d_in[4];
  const float* wV  = (const float*)d_in[5];

  char* ws = (char*)d_ws;
  const size_t NELEM = 4096u * 1024u;
  u16* Qbf  = (u16*)(ws);                        // 8MB  [b,h,s,d] bf16
  u16* Kbf  = (u16*)(ws + (8ull << 20));         // 8MB
  u16* VTbf = (u16*)(ws + (16ull << 20));        // 8MB  [b,h,d,s] bf16
  u16* Xq   = (u16*)(ws + (24ull << 20));
  u16* Xk   = (u16*)(ws + (32ull << 20));
  u16* Xv   = (u16*)(ws + (40ull << 20));
  u16* Wqb  = (u16*)(ws + (48ull << 20));
  u16* Wkb  = (u16*)(ws + (50ull << 20));
  u16* Wvb  = (u16*)(ws + (52ull << 20));
  u16* ctx  = (u16*)(ws + (56ull << 20));        // 8MB bf16 [b,s,1024]

  float* out  = (float*)d_out;
  float* attn = out + NELEM;

  dim3 b256(256);
  cvt6_kernel<<<dim3(4096, 6), b256, 0, stream>>>(inQ, inK, inV, wQ, wK, wV,
                                                  Xq, Xk, Xv, Wqb, Wkb, Wvb,
                                                  (int)(NELEM / 4), 1048576 / 4);

  proj_gemm<<<dim3(32, 8, 3), b256, 0, stream>>>(Xq, Xk, Xv, Wqb, Wkb, Wvb, Qbf, Kbf, VTbf);

  attn_fused<<<dim3(512), dim3(512), 0, stream>>>(Qbf, Kbf, VTbf, attn, ctx);

  ln_kernel<<<dim3(4096), b256, 0, stream>>>(ctx, inQ, out);
}

// Round 14
// 203.714 us; speedup vs baseline: 1.0248x; 1.0248x over previous
//
#include <hip/hip_runtime.h>

typedef unsigned int u32;
typedef unsigned short u16;
typedef __attribute__((ext_vector_type(8))) __bf16 bf16x8;
typedef __attribute__((ext_vector_type(4))) short s16x4;
typedef __attribute__((ext_vector_type(4))) float f32x4;

#define AS1 __attribute__((address_space(1)))
#define AS3 __attribute__((address_space(3)))

__device__ __forceinline__ void gl_lds16(const void* g, void* l) {
  __builtin_amdgcn_global_load_lds((const AS1 void*)g, (AS3 void*)l, 16, 0, 0);
}

__device__ __forceinline__ u16 f2bf(float f) {
  union { float f; u32 u; } v; v.f = f;
  u32 r = v.u + 0x7fffu + ((v.u >> 16) & 1u);
  return (u16)(r >> 16);
}

__device__ __forceinline__ float bf2f(u16 b) {
  union { u32 u; float f; } v; v.u = ((u32)b) << 16; return v.f;
}

__device__ __forceinline__ u32 cvt_pk_bf16(float a, float b) {
  u32 r;
  asm("v_cvt_pk_bf16_f32 %0, %1, %2" : "=v"(r) : "v"(a), "v"(b));
  return r;
}

// 16x16x16 bf16 MFMA (PV consumes P straight from registers).
__device__ __forceinline__ f32x4 mfma16(s16x4 a, s16x4 b, f32x4 c) {
#if __has_builtin(__builtin_amdgcn_mfma_f32_16x16x16bf16_1k)
  return __builtin_amdgcn_mfma_f32_16x16x16bf16_1k(a, b, c, 0, 0, 0);
#else
  asm("v_mfma_f32_16x16x16_bf16 %0, %1, %2, %0" : "+v"(c) : "v"(a), "v"(b));
  return c;
#endif
}

// ---------------- f32 -> bf16 conversion (6 arrays, one launch) ----------------
__global__ void cvt6_kernel(const float* __restrict__ a, const float* __restrict__ b,
                            const float* __restrict__ c, const float* __restrict__ wq,
                            const float* __restrict__ wk, const float* __restrict__ wv,
                            u16* __restrict__ oa, u16* __restrict__ ob, u16* __restrict__ oc,
                            u16* __restrict__ owq, u16* __restrict__ owk, u16* __restrict__ owv,
                            int n4in, int n4w) {
  const int y = blockIdx.y;
  const float* in = (y == 0) ? a : (y == 1) ? b : (y == 2) ? c :
                    (y == 3) ? wq : (y == 4) ? wk : wv;
  u16* out = (y == 0) ? oa : (y == 1) ? ob : (y == 2) ? oc :
             (y == 3) ? owq : (y == 4) ? owk : owv;
  const int n4 = (y < 3) ? n4in : n4w;
  int i = blockIdx.x * blockDim.x + threadIdx.x;
  if (i >= n4) return;
  float4 v = ((const float4*)in)[i];
  ushort4 o;
  o.x = f2bf(v.x); o.y = f2bf(v.y); o.z = f2bf(v.z); o.w = f2bf(v.w);
  ((ushort4*)out)[i] = o;
}

// ---------------- projection GEMM: C[m,n] = sum_k X[m,k] W[n,k] ----------------
// R11-proven config (exact): 128x128 tile, BK=32, 4 waves, 2-phase prefetch
// dbuf, grid (32,8,3) (X-panels XCD-local), branch-free dual operand order,
// in-lane bf16 pack -> LDS transpose -> 1KB full-line stores. NO Q pre-scale
// (R13's scale+exp2 bisected out).
__global__ void __launch_bounds__(256) proj_gemm(
    const u16* __restrict__ Xq, const u16* __restrict__ Xk, const u16* __restrict__ Xv,
    const u16* __restrict__ Wq, const u16* __restrict__ Wk, const u16* __restrict__ Wv,
    u16* __restrict__ Qo, u16* __restrict__ Ko, u16* __restrict__ Vto)
{
  const int which = blockIdx.z;
  const u16* X = (which == 0) ? Xq : (which == 1) ? Xk : Xv;
  const u16* W = (which == 0) ? Wq : (which == 1) ? Wk : Wv;
  const bool isV = (which == 2);

  // 34KB: [0..8191]=As dbuf, [8192..16383]=Bs dbuf; reused as the 128-row x
  // 272B transpose scratch in the epilogue.
  __shared__ u16 smem[17408];

  const int t = threadIdx.x;
  const int lane = t & 63;
  const int w = t >> 6;
  const int wr = w >> 1, wc = w & 1;
  const int lr = lane & 15, lg = lane >> 4;
  const int m0 = blockIdx.x * 128, n0 = blockIdx.y * 128;

  const int e0 = t * 8, e1 = t * 8 + 2048;
  const int r0 = e0 >> 5, c0 = e0 & 31, r1 = e1 >> 5, c1 = e1 & 31;

  // operand-order mapping (wave-uniform, no divergence):
  const int uo = isV ? wr * 64 : wc * 64;   // u-frag row offset (output-row space)
  const int vo = isV ? wc * 64 : wr * 64;   // v-frag row offset (output-col space)

  const f32x4 ZERO = {0.f, 0.f, 0.f, 0.f};
  f32x4 acc[4][4];
  for (int p = 0; p < 4; ++p)
    for (int q = 0; q < 4; ++q) acc[p][q] = ZERO;

  gl_lds16(&X[(size_t)(m0 + r0) * 1024 + c0], &smem[e0]);
  gl_lds16(&X[(size_t)(m0 + r1) * 1024 + c1], &smem[e1]);
  gl_lds16(&W[(size_t)(n0 + r0) * 1024 + c0], &smem[8192 + e0]);
  gl_lds16(&W[(size_t)(n0 + r1) * 1024 + c1], &smem[8192 + e1]);

  for (int ks = 0; ks < 32; ++ks) {
    __syncthreads();
    if (ks + 1 < 32) {
      int kn = (ks + 1) * 32;
      int nb = (ks + 1) & 1;
      gl_lds16(&X[(size_t)(m0 + r0) * 1024 + kn + c0], &smem[nb * 4096 + e0]);
      gl_lds16(&X[(size_t)(m0 + r1) * 1024 + kn + c1], &smem[nb * 4096 + e1]);
      gl_lds16(&W[(size_t)(n0 + r0) * 1024 + kn + c0], &smem[8192 + nb * 4096 + e0]);
      gl_lds16(&W[(size_t)(n0 + r1) * 1024 + kn + c1], &smem[8192 + nb * 4096 + e1]);
    }
    const u16* Ab = &smem[(ks & 1) * 4096];
    const u16* Bb = &smem[8192 + (ks & 1) * 4096];
    const u16* ub = isV ? Ab : Bb;
    const u16* vb = isV ? Bb : Ab;
    bf16x8 u[4], v[4];
#pragma unroll
    for (int p = 0; p < 4; ++p)
      u[p] = *(const bf16x8*)&ub[(uo + p * 16 + lr) * 32 + lg * 8];
#pragma unroll
    for (int q = 0; q < 4; ++q)
      v[q] = *(const bf16x8*)&vb[(vo + q * 16 + lr) * 32 + lg * 8];
#pragma unroll
    for (int p = 0; p < 4; ++p)
#pragma unroll
      for (int q = 0; q < 4; ++q)
        acc[p][q] = __builtin_amdgcn_mfma_f32_16x16x32_bf16(u[p], v[q], acc[p][q], 0, 0, 0);
  }

  // ---- epilogue: pack in-lane (output-row consecutive) -> LDS transpose ----
  __syncthreads();                      // stage buffers dead, reuse as scratch
#pragma unroll
  for (int p = 0; p < 4; ++p) {
#pragma unroll
    for (int q = 0; q < 4; ++q) {
      u32 lo = cvt_pk_bf16(acc[p][q][0], acc[p][q][1]);
      u32 hi = cvt_pk_bf16(acc[p][q][2], acc[p][q][3]);
      int row = vo + q * 16 + lr;       // output-col space (m for QK, n for V)
      int col = uo + p * 16 + lg * 4;   // output-row space (n for QK, m for V)
      *(uint2*)((char*)smem + row * 272 + col * 2) = make_uint2(lo, hi);
    }
  }
  __syncthreads();

  const int h0 = (n0 >> 6);             // first head of this n-panel
  if (!isV) {
    // scratch[m][n]; line = (s, head): 64 d x 2B = 128B. 8 rows x 128B = 1KB/inst.
    u16* O = (which == 0) ? Qo : Ko;
#pragma unroll
    for (int hd = 0; hd < 2; ++hd) {
#pragma unroll
      for (int sb = 0; sb < 4; ++sb) {
        int srow = w * 32 + sb * 8 + (lane >> 3);
        int c = lane & 7;
        uint4 val = *(const uint4*)((const char*)smem + srow * 272 + hd * 128 + c * 16);
        int m = m0 + srow;
        int bb = m >> 11, s = m & 2047;
        *(uint4*)(O + ((size_t)(bb * 16 + h0 + hd) * 2048 + s) * 64 + c * 8) = val;
      }
    }
  } else {
    // scratch[n][m]; line = (head,d): 128 s x 2B = 256B. 4 rows x 256B = 1KB/inst.
    const int bb = m0 >> 11;
    const int sbase = m0 & 2047;        // per-batch row offset
#pragma unroll
    for (int rb = 0; rb < 8; ++rb) {
      int nloc = w * 32 + rb * 4 + (lane >> 4);
      int c = lane & 15;
      uint4 val = *(const uint4*)((const char*)smem + nloc * 272 + c * 16);
      int hd = nloc >> 6, dloc = nloc & 63;
      *(uint4*)(Vto + ((size_t)(bb * 16 + h0 + hd) * 64 + dloc) * 2048 + sbase + c * 8) = val;
    }
  }
}

// ---------------- fused attention: denom + attn write + PV ----------------
// 8 waves, QBLK=128, KVBLK=64, triple-buffered staging, prefetch distance 2,
// counted-vmcnt barriers, reg-P PV, per-wave LDS transpose of the attn tile.
// R14: R12 numerics (__expf(s*0.125), unscaled Q) + R13's PV reorder (PV MFMAs
// between Pf write and its transposed read; stores off the critical path) +
// sched_barrier(0) restored after lgkmcnt(0) (rule #18).
__global__ void __launch_bounds__(512, 4) attn_fused(
    const u16* __restrict__ Qw, const u16* __restrict__ Kw, const u16* __restrict__ VTw,
    float* __restrict__ attn_out, u16* __restrict__ ctx)
{
  __shared__ u16 Ks[3][64 * 64];    // 24KB
  __shared__ u16 Vs[3][64 * 64];    // 24KB
  __shared__ float Pf[8][16 * 36];  // 18KB per-wave f32 P-tile (stride 36 floats)

  const int t = threadIdx.x, lane = t & 63, w = t >> 6;
  const int lr = lane & 15, lg = lane >> 4;
  const int orig = blockIdx.x;
  const int lin = (orig & 7) * 64 + (orig >> 3);   // XCD-chunked bijective (512=8*64)
  const int bh = lin >> 4, q0 = (lin & 15) * 128;

  const u16* Qbase = Qw + (size_t)bh * 2048 * 64;
  const u16* Kbase = Kw + (size_t)bh * 2048 * 64;
  const u16* VTbase = VTw + (size_t)bh * 64 * 2048;

  const int qrow = q0 + w * 16 + lr;
  bf16x8 qa[2];
#pragma unroll
  for (int sl = 0; sl < 2; ++sl)
    qa[sl] = *(const bf16x8*)&Qbase[(size_t)qrow * 64 + sl * 32 + lg * 8];

  const int o = t * 16;
  const int sr = o >> 7;
  const int sg = (((o >> 4) & 7) ^ (sr & 7)) << 3;

  const f32x4 ZERO = {0.f, 0.f, 0.f, 0.f};

  // ================= phase 1: softmax denominator =================
  gl_lds16(&Kbase[(size_t)sr * 64 + sg], (char*)&Ks[0][0] + o);
  gl_lds16(&Kbase[(size_t)(64 + sr) * 64 + sg], (char*)&Ks[1][0] + o);
  __syncthreads();

  float lacc = 0.f;
  for (int it = 0; it < 32; ++it) {
    if (it + 2 < 32)
      gl_lds16(&Kbase[(size_t)((it + 2) * 64 + sr) * 64 + sg],
               (char*)&Ks[(it + 2) % 3][0] + o);
    const u16* Kb = &Ks[it % 3][0];
    f32x4 sacc[4];
#pragma unroll
    for (int jj = 0; jj < 4; ++jj) sacc[jj] = ZERO;
#pragma unroll
    for (int sl = 0; sl < 2; ++sl) {
#pragma unroll
      for (int jj = 0; jj < 4; ++jj) {
        int R = jj * 16 + lr;
        int gs = lg + sl * 4;
        bf16x8 kb = *(const bf16x8*)&Kb[R * 64 + ((gs ^ (R & 7)) << 3)];
        sacc[jj] = __builtin_amdgcn_mfma_f32_16x16x32_bf16(kb, qa[sl], sacc[jj], 0, 0, 0);
      }
    }
#pragma unroll
    for (int jj = 0; jj < 4; ++jj)
#pragma unroll
      for (int r = 0; r < 4; ++r)
        lacc += __expf(sacc[jj][r] * 0.125f);

    if (it < 31) {
      __builtin_amdgcn_sched_barrier(0);
      if (it == 30) { asm volatile("s_waitcnt vmcnt(0)" ::: "memory"); }
      else         { asm volatile("s_waitcnt vmcnt(2)" ::: "memory"); }
      __builtin_amdgcn_s_barrier();
      __builtin_amdgcn_sched_barrier(0);
    }
  }
  lacc += __shfl_xor(lacc, 16);
  lacc += __shfl_xor(lacc, 32);               // l for q = qrow (uniform over lg)
  const float linv = 1.f / lacc;

  // ================= phase 2: attn write + PV =================
  __syncthreads();                            // all phase-1 LDS reads done
  gl_lds16(&Kbase[(size_t)sr * 64 + sg], (char*)&Ks[0][0] + o);
  gl_lds16(&VTbase[(size_t)sr * 2048 + sg], (char*)&Vs[0][0] + o);
  gl_lds16(&Kbase[(size_t)(64 + sr) * 64 + sg], (char*)&Ks[1][0] + o);
  gl_lds16(&VTbase[(size_t)sr * 2048 + 64 + sg], (char*)&Vs[1][0] + o);
  __syncthreads();                            // prologue staging visible

  f32x4 acc_o[4];                             // acc_o[dd]: d = dd*16+lg*4+r, q = lr
#pragma unroll
  for (int j = 0; j < 4; ++j) acc_o[j] = ZERO;

  float* ablk = attn_out + ((size_t)bh * 2048 + q0 + w * 16) * 2048;  // wave's 16 rows
  float* Pfw = &Pf[w][0];

  for (int it = 0; it < 32; ++it) {
    const int kt = it * 64;
    if (it + 2 < 32) {                         // prefetch distance 2
      const int nb = (it + 2) % 3;
      gl_lds16(&Kbase[(size_t)(kt + 128 + sr) * 64 + sg], (char*)&Ks[nb][0] + o);
      gl_lds16(&VTbase[(size_t)sr * 2048 + kt + 128 + sg], (char*)&Vs[nb][0] + o);
    }
    const u16* Kb = &Ks[it % 3][0];
    const u16* Vb = &Vs[it % 3][0];

    // S^T tile: lane holds S[k=kt+jj*16+lg*4+r][q=qrow]
    f32x4 sacc[4];
#pragma unroll
    for (int jj = 0; jj < 4; ++jj) sacc[jj] = ZERO;
#pragma unroll
    for (int sl = 0; sl < 2; ++sl) {
#pragma unroll
      for (int jj = 0; jj < 4; ++jj) {
        int R = jj * 16 + lr;
        int gs = lg + sl * 4;
        bf16x8 kb = *(const bf16x8*)&Kb[R * 64 + ((gs ^ (R & 7)) << 3)];
        sacc[jj] = __builtin_amdgcn_mfma_f32_16x16x32_bf16(kb, qa[sl], sacc[jj], 0, 0, 0);
      }
    }

    // per half-tile: exp+pack+Pf write -> PV MFMAs (cover LDS latency) ->
    // lgkmcnt -> transposed full-line stores.
    s16x4 pb[4];
#pragma unroll
    for (int hh = 0; hh < 2; ++hh) {
#pragma unroll
      for (int j2 = 0; j2 < 2; ++j2) {
        const int jj = hh * 2 + j2;
        f32x4 e;
#pragma unroll
        for (int r = 0; r < 4; ++r)
          e[r] = __expf(sacc[jj][r] * 0.125f);
        f32x4 st = e * linv;
        *(f32x4*)&Pfw[lr * 36 + j2 * 16 + lg * 4] = st;   // [q=lr][kofs]
        union { u32 w2[2]; s16x4 v; } pk;
        pk.w2[0] = cvt_pk_bf16(e[0], e[1]);
        pk.w2[1] = cvt_pk_bf16(e[2], e[3]);
        pb[jj] = pk.v;
      }
      // PV for this half's jj pair runs between Pf write and read
#pragma unroll
      for (int dd = 0; dd < 4; ++dd) {
        const int R = dd * 16 + lr;
        const int rowbase = R * 64;
        const int rsw = (R & 7);
#pragma unroll
        for (int j2 = 0; j2 < 2; ++j2) {
          const int jj = hh * 2 + j2;
          const int slot = 2 * jj + (lg >> 1);
          s16x4 va = *(const s16x4*)&Vb[rowbase + ((slot ^ rsw) << 3) + (lg & 1) * 4];
          acc_o[dd] = mfma16(va, pb[jj], acc_o[dd]);
        }
      }
      asm volatile("s_waitcnt lgkmcnt(0)" ::: "memory");
      __builtin_amdgcn_sched_barrier(0);
#pragma unroll
      for (int rb = 0; rb < 2; ++rb) {
        const int rrow = rb * 8 + (lane >> 3);
        f32x4 v = *(const f32x4*)&Pfw[rrow * 36 + (lane & 7) * 4];
        float* dst = ablk + (size_t)rrow * 2048 + kt + hh * 32 + (lane & 7) * 4;
        __builtin_nontemporal_store(v, (f32x4*)dst);
      }
    }

    if (it < 31) {
      __builtin_amdgcn_sched_barrier(0);
      if (it == 30) { asm volatile("s_waitcnt vmcnt(8)" ::: "memory"); }
      else          { asm volatile("s_waitcnt vmcnt(10)" ::: "memory"); }
      __builtin_amdgcn_s_barrier();
      __builtin_amdgcn_sched_barrier(0);
    }
  }

  // epilogue: ctx = O / l (bf16), q = lr (lane-local linv), d consecutive in r
  const int bb = bh >> 4, h = bh & 15;
  u16* crow = ctx + ((size_t)bb * 2048 + qrow) * 1024 + h * 64;
#pragma unroll
  for (int dd = 0; dd < 4; ++dd) {
    union { u32 w2[2]; } pk;
    pk.w2[0] = cvt_pk_bf16(acc_o[dd][0] * linv, acc_o[dd][1] * linv);
    pk.w2[1] = cvt_pk_bf16(acc_o[dd][2] * linv, acc_o[dd][3] * linv);
    *(uint2*)&crow[dd * 16 + lg * 4] = make_uint2(pk.w2[0], pk.w2[1]);
  }
}

// ---------------- residual + LayerNorm (ctx bf16, residual f32) ----------------
__global__ void __launch_bounds__(256) ln_kernel(
    const u16* __restrict__ ctx, const float* __restrict__ res, float* __restrict__ out)
{
  __shared__ float red[8];
  int row = blockIdx.x;
  int t = threadIdx.x;
  int lane = t & 63, w = t >> 6;
  size_t base = (size_t)row * 1024 + t * 4;
  ushort4 cv = *(const ushort4*)&ctx[base];
  float4 rs = *(const float4*)&res[base];
  float x0 = bf2f(cv.x) + rs.x, x1 = bf2f(cv.y) + rs.y;
  float x2 = bf2f(cv.z) + rs.z, x3 = bf2f(cv.w) + rs.w;
  float s = x0 + x1 + x2 + x3;
  float q = x0 * x0 + x1 * x1 + x2 * x2 + x3 * x3;
#pragma unroll
  for (int off = 1; off < 64; off <<= 1) {
    s += __shfl_xor(s, off);
    q += __shfl_xor(q, off);
  }
  if (lane == 0) { red[w] = s; red[w + 4] = q; }
  __syncthreads();
  s = red[0] + red[1] + red[2] + red[3];
  q = red[4] + red[5] + red[6] + red[7];
  float mu = s * (1.f / 1024.f);
  float var = q * (1.f / 1024.f) - mu * mu;
  float inv = rsqrtf(var + 1e-5f);
  float4 o;
  o.x = (x0 - mu) * inv; o.y = (x1 - mu) * inv; o.z = (x2 - mu) * inv; o.w = (x3 - mu) * inv;
  *(float4*)&out[base] = o;
}

extern "C" void kernel_launch(void* const* d_in, const int* in_sizes, int n_in,
                              void* d_out, int out_size, void* d_ws, size_t ws_size,
                              hipStream_t stream) {
  (void)in_sizes; (void)n_in; (void)out_size; (void)ws_size;
  const float* inQ = (const float*)d_in[0];
  const float* inK = (const float*)d_in[1];
  const float* inV = (const float*)d_in[2];
  const float* wQ  = (const float*)d_in[3];
  const float* wK  = (const float*)d_in[4];
  const float* wV  = (const float*)d_in[5];

  char* ws = (char*)d_ws;
  const size_t NELEM = 4096u * 1024u;
  u16* Qbf  = (u16*)(ws);                        // 8MB  [b,h,s,d] bf16
  u16* Kbf  = (u16*)(ws + (8ull << 20));         // 8MB
  u16* VTbf = (u16*)(ws + (16ull << 20));        // 8MB  [b,h,d,s] bf16
  u16* Xq   = (u16*)(ws + (24ull << 20));
  u16* Xk   = (u16*)(ws + (32ull << 20));
  u16* Xv   = (u16*)(ws + (40ull << 20));
  u16* Wqb  = (u16*)(ws + (48ull << 20));
  u16* Wkb  = (u16*)(ws + (50ull << 20));
  u16* Wvb  = (u16*)(ws + (52ull << 20));
  u16* ctx  = (u16*)(ws + (56ull << 20));        // 8MB bf16 [b,s,1024]

  float* out  = (float*)d_out;
  float* attn = out + NELEM;

  dim3 b256(256);
  cvt6_kernel<<<dim3(4096, 6), b256, 0, stream>>>(inQ, inK, inV, wQ, wK, wV,
                                                  Xq, Xk, Xv, Wqb, Wkb, Wvb,
                                                  (int)(NELEM / 4), 1048576 / 4);

  proj_gemm<<<dim3(32, 8, 3), b256, 0, stream>>>(Xq, Xk, Xv, Wqb, Wkb, Wvb, Qbf, Kbf, VTbf);

  attn_fused<<<dim3(512), dim3(512), 0, stream>>>(Qbf, Kbf, VTbf, attn, ctx);

  ln_kernel<<<dim3(4096), b256, 0, stream>>>(ctx, inQ, out);
}